// Round 1
// baseline (5029.446 us; speedup 1.0000x reference)
//
#include <hip/hip_runtime.h>

#define B 4
#define CIN 256
#define T 8192
#define NLAYERS 24
#define RES 128
#define GATE 256
#define GH 128
#define TT 64

#define SQRT_HALF 0.70710678118654752f
#define SKIP_SCALE 0.20412414523193150f  // (1/24)^0.5

// ---------------------------------------------------------------------------
// Generic pointwise conv:  out[b,o,t] = act_out( W[o,:] . act_in(in[b,:,t]) + bias[o] )
// Block: 256 threads, tile = TT time steps, all CO channels.
// Thread tile: 8 o-channels x TV t-values.
// ---------------------------------------------------------------------------
template<int CI, int CO, bool RELU_IN, bool RELU_OUT>
__global__ __launch_bounds__(256)
void pconv_kernel(const float* __restrict__ in, const float* __restrict__ w,
                  const float* __restrict__ bias, float* __restrict__ out,
                  float in_scale)
{
    constexpr int NOG = CO / 8;      // o-groups (8 channels each)
    constexpr int TG  = 256 / NOG;   // t-groups
    constexpr int TV  = TT / TG;     // t per thread
    __shared__ float in_s[CI][TT];   // CI=256 -> 64KB, CI=128 -> 32KB

    const int t0  = blockIdx.x * TT;
    const int b   = blockIdx.y;
    const int tid = threadIdx.x;

    for (int idx = tid; idx < CI * TT; idx += 256) {
        int c = idx >> 6, j = idx & 63;
        float v = in[((size_t)b * CI + c) * T + t0 + j];
        if (RELU_IN) { v *= in_scale; v = fmaxf(v, 0.f); }
        in_s[c][j] = v;
    }
    __syncthreads();

    const int og = tid / TG, tg = tid % TG;
    const int o0 = og * 8, tl0 = tg * TV;

    float acc[8][TV];
    #pragma unroll
    for (int u = 0; u < 8; u++)
        #pragma unroll
        for (int v = 0; v < TV; v++) acc[u][v] = 0.f;

    for (int c = 0; c < CI; c++) {
        float xv[TV];
        #pragma unroll
        for (int v = 0; v < TV; v++) xv[v] = in_s[c][tl0 + v];
        #pragma unroll
        for (int u = 0; u < 8; u++) {
            float wv = w[(size_t)(o0 + u) * CI + c];
            #pragma unroll
            for (int v = 0; v < TV; v++) acc[u][v] = fmaf(wv, xv[v], acc[u][v]);
        }
    }

    #pragma unroll
    for (int u = 0; u < 8; u++) {
        float bv = bias[o0 + u];
        #pragma unroll
        for (int v = 0; v < TV; v++) {
            float r = acc[u][v] + bv;
            if (RELU_OUT) r = fmaxf(r, 0.f);
            out[((size_t)b * CO + o0 + u) * T + t0 + tl0 + v] = r;
        }
    }
}

// ---------------------------------------------------------------------------
// Dilated causal conv (K=3) + gated activation, fused:
//   y[b,o,t] = sum_{c,k} cw[o,c,k] * h[b,c,t-(2-k)*d] + cb[o]   (h[t<0]=0)
//   z[b,o,t] = tanh(y[o]) * sigmoid(y[o+128]),  o in [0,128)
// Each thread computes BOTH gate halves for its 8 channels -> gate in-register.
// ---------------------------------------------------------------------------
__global__ __launch_bounds__(256)
void convgate_kernel(const float* __restrict__ h, const float* __restrict__ cw,
                     const float* __restrict__ cb, float* __restrict__ z, int d)
{
    __shared__ float h_s[RES][128];  // 64KB; cols j in [0, TT+2d), t = t0-2d+j

    const int t0  = blockIdx.x * TT;
    const int b   = blockIdx.y;
    const int tid = threadIdx.x;
    const int W   = TT + 2 * d;      // <= 128

    for (int idx = tid; idx < RES * W; idx += 256) {
        int c = idx / W, j = idx - c * W;
        int gt = t0 - 2 * d + j;
        h_s[c][j] = (gt >= 0) ? h[((size_t)b * RES + c) * T + gt] : 0.f;
    }
    __syncthreads();

    const int og = tid >> 4, tg = tid & 15;   // 16 o-groups x 16 t-groups
    const int o0 = og * 8, tl0 = tg * 4;

    float acc_a[8][4], acc_g[8][4];
    #pragma unroll
    for (int u = 0; u < 8; u++)
        #pragma unroll
        for (int v = 0; v < 4; v++) { acc_a[u][v] = 0.f; acc_g[u][v] = 0.f; }

    for (int c = 0; c < RES; c++) {
        const float* hrow = h_s[c];
        float hv[3][4];
        #pragma unroll
        for (int k = 0; k < 3; k++)
            #pragma unroll
            for (int v = 0; v < 4; v++) hv[k][v] = hrow[tl0 + v + k * d];
        #pragma unroll
        for (int u = 0; u < 8; u++) {
            const float* wa = cw + ((size_t)(o0 + u) * RES + c) * 3;
            const float* wg = wa + (size_t)128 * RES * 3;
            #pragma unroll
            for (int k = 0; k < 3; k++) {
                float wva = wa[k], wvg = wg[k];
                #pragma unroll
                for (int v = 0; v < 4; v++) {
                    acc_a[u][v] = fmaf(wva, hv[k][v], acc_a[u][v]);
                    acc_g[u][v] = fmaf(wvg, hv[k][v], acc_g[u][v]);
                }
            }
        }
    }

    #pragma unroll
    for (int u = 0; u < 8; u++) {
        float ba = cb[o0 + u], bg = cb[o0 + u + 128];
        #pragma unroll
        for (int v = 0; v < 4; v++) {
            float a = acc_a[u][v] + ba;
            float g = acc_g[u][v] + bg;
            float zt = tanhf(a) * (1.f / (1.f + __expf(-g)));
            z[((size_t)b * GH + o0 + u) * T + t0 + tl0 + v] = zt;
        }
    }
}

// ---------------------------------------------------------------------------
// skip += skip_w @ z + skip_b ;  h_out = (out_w @ z + out_b + h_in) * sqrt(1/2)
// 256 combined output channels: o<128 -> skip row o, o>=128 -> out row o-128.
// ---------------------------------------------------------------------------
__global__ __launch_bounds__(256)
void skipout_kernel(const float* __restrict__ z, const float* __restrict__ h_in,
                    const float* __restrict__ sw, const float* __restrict__ sb,
                    const float* __restrict__ ow, const float* __restrict__ ob,
                    float* __restrict__ h_out, float* __restrict__ sk, int first)
{
    __shared__ float z_s[GH][TT];    // 32KB

    const int t0  = blockIdx.x * TT;
    const int b   = blockIdx.y;
    const int tid = threadIdx.x;

    for (int idx = tid; idx < GH * TT; idx += 256) {
        int c = idx >> 6, j = idx & 63;
        z_s[c][j] = z[((size_t)b * GH + c) * T + t0 + j];
    }
    __syncthreads();

    const int og = tid >> 3, tg = tid & 7;   // 32 o-groups x 8 t-groups
    const int o0 = og * 8, tl0 = tg * 8;
    const bool is_skip = (og < 16);
    const int ro0 = o0 & 127;
    const float* wmat = is_skip ? sw : ow;

    float acc[8][8];
    #pragma unroll
    for (int u = 0; u < 8; u++)
        #pragma unroll
        for (int v = 0; v < 8; v++) acc[u][v] = 0.f;

    for (int c = 0; c < GH; c++) {
        float zv[8];
        #pragma unroll
        for (int v = 0; v < 8; v++) zv[v] = z_s[c][tl0 + v];
        #pragma unroll
        for (int u = 0; u < 8; u++) {
            float wv = wmat[(size_t)(ro0 + u) * GH + c];
            #pragma unroll
            for (int v = 0; v < 8; v++) acc[u][v] = fmaf(wv, zv[v], acc[u][v]);
        }
    }

    if (is_skip) {
        #pragma unroll
        for (int u = 0; u < 8; u++) {
            float bv = sb[ro0 + u];
            #pragma unroll
            for (int v = 0; v < 8; v++) {
                size_t off = ((size_t)b * GH + ro0 + u) * T + t0 + tl0 + v;
                float prev = first ? 0.f : sk[off];
                sk[off] = prev + acc[u][v] + bv;
            }
        }
    } else {
        #pragma unroll
        for (int u = 0; u < 8; u++) {
            float bv = ob[ro0 + u];
            #pragma unroll
            for (int v = 0; v < 8; v++) {
                size_t off = ((size_t)b * RES + ro0 + u) * T + t0 + tl0 + v;
                h_out[off] = (acc[u][v] + bv + h_in[off]) * SQRT_HALF;
            }
        }
    }
}

// ---------------------------------------------------------------------------
extern "C" void kernel_launch(void* const* d_in, const int* in_sizes, int n_in,
                              void* d_out, int out_size, void* d_ws, size_t ws_size,
                              hipStream_t stream)
{
    const float* x       = (const float*)d_in[0];
    const float* first_w = (const float*)d_in[1];
    const float* first_b = (const float*)d_in[2];
    const float* conv_w  = (const float*)d_in[3];
    const float* conv_b  = (const float*)d_in[4];
    const float* out_w   = (const float*)d_in[5];
    const float* out_b   = (const float*)d_in[6];
    const float* skip_w  = (const float*)d_in[7];
    const float* skip_b  = (const float*)d_in[8];
    const float* last1_w = (const float*)d_in[9];
    const float* last1_b = (const float*)d_in[10];
    const float* last2_w = (const float*)d_in[11];
    const float* last2_b = (const float*)d_in[12];
    float* out = (float*)d_out;

    const size_t NBT = (size_t)B * RES * T;   // 4,194,304 floats (16 MB)
    float* ws  = (float*)d_ws;
    float* h_a = ws;
    float* h_b = ws + NBT;
    float *zbuf, *skbuf;
    if (ws_size >= 4 * NBT * sizeof(float)) {
        zbuf  = ws + 2 * NBT;
        skbuf = ws + 3 * NBT;
    } else {
        // fall back to using d_out (2*NBT floats) as scratch for z and skips;
        // both are dead before the final kernel writes d_out.
        zbuf  = out;
        skbuf = out + NBT;
    }

    dim3 grid(T / TT, B), blk(256);

    pconv_kernel<CIN, RES, false, false><<<grid, blk, 0, stream>>>(x, first_w, first_b, h_a, 1.f);

    float* hc = h_a;
    float* hn = h_b;
    for (int i = 0; i < NLAYERS; i++) {
        int d = 1 << (i % 6);
        convgate_kernel<<<grid, blk, 0, stream>>>(
            hc, conv_w + (size_t)i * GATE * RES * 3, conv_b + (size_t)i * GATE, zbuf, d);
        skipout_kernel<<<grid, blk, 0, stream>>>(
            zbuf, hc,
            skip_w + (size_t)i * GH * GH, skip_b + (size_t)i * GH,
            out_w + (size_t)i * RES * GH, out_b + (size_t)i * RES,
            hn, skbuf, i == 0 ? 1 : 0);
        float* t = hc; hc = hn; hn = t;
    }

    // hn is the free buffer now. s1 = relu(last1 @ relu(skips*scale) + b1)
    pconv_kernel<GH, GH, true, true><<<grid, blk, 0, stream>>>(skbuf, last1_w, last1_b, hn, SKIP_SCALE);
    pconv_kernel<GH, CIN, false, false><<<grid, blk, 0, stream>>>(hn, last2_w, last2_b, out, 1.f);
}

// Round 2
// 828.992 us; speedup vs baseline: 6.0669x; 6.0669x over previous
//
#include <hip/hip_runtime.h>

#define B 4
#define CIN 256
#define T 8192
#define NL 24
#define TP (64 + T + 8)      // padded rows for bf16 h: 64 zero halo + T + 8 overshoot
#define TT 128               // layer kernel time tile
#define SQRT_HALF 0.70710678118654752f
#define SKIP_SCALE 0.20412414523193150f  // (1/24)^0.5

typedef unsigned short u16;
typedef __attribute__((ext_vector_type(4))) float f32x4;
typedef __attribute__((ext_vector_type(8))) short s16x8;
typedef __attribute__((ext_vector_type(4))) short s16x4;

__device__ inline u16 f2bf(float f) {            // RNE float->bf16
  unsigned u = __float_as_uint(f);
  return (u16)((u + 0x7fffu + ((u >> 16) & 1u)) >> 16);
}

__device__ inline void gload_lds16(const void* g, void* l) {
  __builtin_amdgcn_global_load_lds(
      (const __attribute__((address_space(1))) unsigned*)g,
      (__attribute__((address_space(3))) unsigned*)l, 16, 0, 0);
}

__device__ inline float gate_fn(float a, float g) {
  // tanh(a)*sigmoid(g), branchless/overflow-safe, single divide
  float af = fminf(fabsf(a), 20.f);
  float E = __expf(2.f * af);
  float F = __expf(-g);
  float z = (E - 1.f) / ((E + 1.f) * (1.f + F));
  return copysignf(z, a);
}

// ---------------- weight prep ----------------
__global__ void cvt_convw(const float* __restrict__ src, u16* __restrict__ dst) {
  int i = blockIdx.x * 256 + threadIdx.x;          // N = 24*3*256*128
  if (i >= NL * 3 * 256 * 128) return;
  int c = i & 127, o = (i >> 7) & 255, kk = (i >> 15) % 3, l = (i >> 15) / 3;
  dst[i] = f2bf(src[(((size_t)l * 256 + o) * 128 + c) * 3 + kk]);
}
__global__ void cvt_sow(const float* __restrict__ skw, const float* __restrict__ otw,
                        u16* __restrict__ dst) {
  int i = blockIdx.x * 256 + threadIdx.x;          // N = 24*256*128
  if (i >= NL * 256 * 128) return;
  int c = i & 127, r = (i >> 7) & 255, l = i >> 15;
  float v = (r < 128) ? skw[((size_t)l * 128 + r) * 128 + c]
                      : otw[((size_t)l * 128 + (r - 128)) * 128 + c];
  dst[i] = f2bf(v);
}
__global__ void cvt_plain(const float* __restrict__ s, u16* __restrict__ d, int n) {
  int i = blockIdx.x * 256 + threadIdx.x;
  if (i < n) d[i] = f2bf(s[i]);
}
__global__ void padzero(u16* __restrict__ hb) {
  int i = blockIdx.x * 256 + threadIdx.x;          // N = 4*64*128
  if (i >= B * 64 * 128) return;
  int c = i & 127, r = (i >> 7) & 63, b = i >> 13;
  hb[((size_t)b * TP + r) * 128 + c] = 0;
}

// ---------------- first 1x1 conv: h = first_w @ x + first_b ----------------
__global__ __launch_bounds__(256, 2)
void first_kernel(const float* __restrict__ x, const u16* __restrict__ wf,
                  const float* __restrict__ fb, float* __restrict__ hf,
                  u16* __restrict__ hb) {
  __shared__ u16 xT[64 * 256];    // 32KB, rows 512B, swizzled
  __shared__ u16 hoT[64 * 128];   // 16KB
  const int tid = threadIdx.x, wv = tid >> 6, lane = tid & 63, lo = lane & 15, hi = lane >> 4;
  const int t0 = blockIdx.x * 64, b = blockIdx.y;

  for (int it = 0; it < 16; it++) {                 // transpose-cvt x tile
    int idx = tid + it * 256;                       // 4096 float4
    int c = idx >> 4, t4 = (idx & 15) << 2;
    f32x4 v = *(const f32x4*)(x + ((size_t)b * CIN + c) * T + t0 + t4);
    #pragma unroll
    for (int i = 0; i < 4; i++) {
      int t = t4 + i;
      *(u16*)((char*)xT + t * 512 + ((c * 2) ^ ((t & 7) << 4))) = f2bf(v[i]);
    }
  }
  __syncthreads();

  f32x4 acc[2][4];
  #pragma unroll
  for (int m = 0; m < 2; m++)
    #pragma unroll
    for (int n = 0; n < 4; n++) acc[m][n] = (f32x4){0.f, 0.f, 0.f, 0.f};

  for (int s = 0; s < 8; s++) {
    s16x8 af[2], bf[4];
    #pragma unroll
    for (int m = 0; m < 2; m++)
      af[m] = *(const s16x8*)(wf + (size_t)(wv * 32 + m * 16 + lo) * CIN + s * 32 + hi * 8);
    #pragma unroll
    for (int n = 0; n < 4; n++) {
      int t = n * 16 + lo;
      bf[n] = *(const s16x8*)((const char*)xT + t * 512 + ((s * 64 + hi * 16) ^ ((t & 7) << 4)));
    }
    #pragma unroll
    for (int m = 0; m < 2; m++)
      #pragma unroll
      for (int n = 0; n < 4; n++)
        acc[m][n] = __builtin_amdgcn_mfma_f32_16x16x32_bf16(af[m], bf[n], acc[m][n], 0, 0, 0);
  }

  #pragma unroll
  for (int m = 0; m < 2; m++) {
    int c0 = wv * 32 + m * 16 + hi * 4;
    f32x4 bv = *(const f32x4*)(fb + c0);
    #pragma unroll
    for (int n = 0; n < 4; n++) {
      int t = n * 16 + lo;
      f32x4 h = acc[m][n] + bv;
      *(f32x4*)(hf + ((size_t)b * T + t0 + t) * 128 + c0) = h;
      s16x4 pk;
      #pragma unroll
      for (int j = 0; j < 4; j++) pk[j] = (short)f2bf(h[j]);
      *(s16x4*)((char*)hoT + t * 256 + ((c0 * 2) ^ ((t & 7) << 4))) = pk;
    }
  }
  __syncthreads();
  u16* gd = hb + ((size_t)b * TP + 64 + t0) * 128;
  for (int i = tid; i < 1024; i += 256)
    *(s16x8*)((char*)gd + i * 16) = *(const s16x8*)((const char*)hoT + i * 16);
}

// ---------------- fused layer: dilated conv + gate + skip + residual ----------------
__global__ __launch_bounds__(512, 2)
void layer_kernel(const u16* __restrict__ hbin, u16* __restrict__ hbout,
                  float* __restrict__ hf, float* __restrict__ skip,
                  const u16* __restrict__ wcv, const float* __restrict__ cb,
                  const u16* __restrict__ wso, const float* __restrict__ sb,
                  const float* __restrict__ ob, int d, int first) {
  __shared__ u16 h_s[196 * 128];  // 50176B: up to 192 halo rows + overshoot
  __shared__ u16 zh[128 * 128];   // 32KB: zT, then reused as hoT
  const int tid = threadIdx.x, wv = tid >> 6, lane = tid & 63, lo = lane & 15, hi = lane >> 4;
  const int t0 = blockIdx.x * TT, b = blockIdx.y;
  const int R = TT + 2 * d;
  const int nch = (R * 256 + 1023) >> 10;

  const char* src = (const char*)(hbin + ((size_t)b * TP + (64 + t0 - 2 * d)) * 128);
  for (int ch = wv; ch < nch; ch += 8)
    gload_lds16(src + ch * 1024 + lane * 16, (char*)h_s + ch * 1024);
  __syncthreads();

  // ---- conv GEMM: wave owns a-rows [wv*16,+16) and g-rows [128+wv*16,+16)
  f32x4 acc[2][8];
  #pragma unroll
  for (int m = 0; m < 2; m++)
    #pragma unroll
    for (int n = 0; n < 8; n++) acc[m][n] = (f32x4){0.f, 0.f, 0.f, 0.f};
  const int oa = wv * 16, og = 128 + wv * 16;

  for (int k = 0; k < 3; k++) {
    const int jb = k * d;
    const int st = ((lo + (k + 6) * d) & 7) << 4;   // (t_read & 7) << 4
    for (int s = 0; s < 4; s++) {
      s16x8 af0 = *(const s16x8*)(wcv + ((size_t)(k * 256 + oa + lo)) * 128 + s * 32 + hi * 8);
      s16x8 af1 = *(const s16x8*)(wcv + ((size_t)(k * 256 + og + lo)) * 128 + s * 32 + hi * 8);
      const int cbyte = s * 64 + hi * 16;
      s16x8 bf[8];
      #pragma unroll
      for (int n = 0; n < 8; n++) {
        int j = n * 16 + lo + jb;
        bf[n] = *(const s16x8*)((const char*)h_s + j * 256 + (cbyte ^ st));
      }
      #pragma unroll
      for (int n = 0; n < 8; n++) {
        acc[0][n] = __builtin_amdgcn_mfma_f32_16x16x32_bf16(af0, bf[n], acc[0][n], 0, 0, 0);
        acc[1][n] = __builtin_amdgcn_mfma_f32_16x16x32_bf16(af1, bf[n], acc[1][n], 0, 0, 0);
      }
    }
  }

  // ---- gate -> zT (bf16, swizzled)
  f32x4 ba = *(const f32x4*)(cb + oa + hi * 4);
  f32x4 bg = *(const f32x4*)(cb + og + hi * 4);
  #pragma unroll
  for (int n = 0; n < 8; n++) {
    int t = n * 16 + lo;
    s16x4 pk;
    #pragma unroll
    for (int j = 0; j < 4; j++)
      pk[j] = (short)f2bf(gate_fn(acc[0][n][j] + ba[j], acc[1][n][j] + bg[j]));
    *(s16x4*)((char*)zh + t * 256 + (((oa + hi * 4) * 2) ^ ((t & 7) << 4))) = pk;
  }
  __syncthreads();

  // ---- skip/out GEMM: combined M=256 rows, wave rows [wv*32,+32)
  f32x4 ac2[2][8];
  #pragma unroll
  for (int m = 0; m < 2; m++)
    #pragma unroll
    for (int n = 0; n < 8; n++) ac2[m][n] = (f32x4){0.f, 0.f, 0.f, 0.f};
  const int ro = wv * 32;
  for (int s = 0; s < 4; s++) {
    s16x8 af0 = *(const s16x8*)(wso + (size_t)(ro + lo) * 128 + s * 32 + hi * 8);
    s16x8 af1 = *(const s16x8*)(wso + (size_t)(ro + 16 + lo) * 128 + s * 32 + hi * 8);
    const int cbyte = s * 64 + hi * 16;
    s16x8 bf[8];
    #pragma unroll
    for (int n = 0; n < 8; n++) {
      int t = n * 16 + lo;
      bf[n] = *(const s16x8*)((const char*)zh + t * 256 + (cbyte ^ ((t & 7) << 4)));
    }
    #pragma unroll
    for (int n = 0; n < 8; n++) {
      ac2[0][n] = __builtin_amdgcn_mfma_f32_16x16x32_bf16(af0, bf[n], ac2[0][n], 0, 0, 0);
      ac2[1][n] = __builtin_amdgcn_mfma_f32_16x16x32_bf16(af1, bf[n], ac2[1][n], 0, 0, 0);
    }
  }
  __syncthreads();  // zT dead; zh becomes hoT

  if (wv < 4) {   // skip channels wv*32 + ...
    #pragma unroll
    for (int m = 0; m < 2; m++) {
      int c0 = wv * 32 + m * 16 + hi * 4;
      f32x4 sb4 = *(const f32x4*)(sb + c0);
      #pragma unroll
      for (int n = 0; n < 8; n++) {
        size_t off = ((size_t)b * T + t0 + n * 16 + lo) * 128 + c0;
        f32x4 r = ac2[m][n] + sb4;
        if (!first) r += *(const f32x4*)(skip + off);
        *(f32x4*)(skip + off) = r;
      }
    }
  } else {        // residual channels (wv-4)*32 + ...
    #pragma unroll
    for (int m = 0; m < 2; m++) {
      int c0 = (wv - 4) * 32 + m * 16 + hi * 4;
      f32x4 ob4 = *(const f32x4*)(ob + c0);
      #pragma unroll
      for (int n = 0; n < 8; n++) {
        int tl = n * 16 + lo;
        size_t off = ((size_t)b * T + t0 + tl) * 128 + c0;
        f32x4 hn = (ac2[m][n] + ob4 + *(const f32x4*)(hf + off)) * SQRT_HALF;
        *(f32x4*)(hf + off) = hn;
        s16x4 pk;
        #pragma unroll
        for (int j = 0; j < 4; j++) pk[j] = (short)f2bf(hn[j]);
        *(s16x4*)((char*)zh + tl * 256 + ((c0 * 2) ^ ((tl & 7) << 4))) = pk;
      }
    }
  }
  __syncthreads();
  u16* gd = hbout + ((size_t)b * TP + 64 + t0) * 128;
  for (int i = tid; i < 2048; i += 512)
    *(s16x8*)((char*)gd + i * 16) = *(const s16x8*)((const char*)zh + i * 16);
}

// ---------------- head1: s1 = relu(last1 @ relu(skip*scale) + b1) ----------------
__global__ __launch_bounds__(256, 2)
void head1_kernel(const float* __restrict__ skip, const u16* __restrict__ w1,
                  const float* __restrict__ b1, u16* __restrict__ s1) {
  __shared__ u16 sT[64 * 128];
  const int tid = threadIdx.x, wv = tid >> 6, lane = tid & 63, lo = lane & 15, hi = lane >> 4;
  const int t0 = blockIdx.x * 64, b = blockIdx.y;

  for (int it = 0; it < 8; it++) {
    int idx = tid + it * 256;                 // 2048 = 64 rows * 32 f32x4
    int t = idx >> 5, c4 = idx & 31;
    f32x4 v = *(const f32x4*)(skip + ((size_t)b * T + t0 + t) * 128 + c4 * 4);
    s16x4 pk;
    #pragma unroll
    for (int i = 0; i < 4; i++) pk[i] = (short)f2bf(fmaxf(v[i] * SKIP_SCALE, 0.f));
    *(s16x4*)((char*)sT + t * 256 + ((c4 * 8) ^ ((t & 7) << 4))) = pk;
  }
  __syncthreads();

  f32x4 acc[2][4];
  #pragma unroll
  for (int m = 0; m < 2; m++)
    #pragma unroll
    for (int n = 0; n < 4; n++) acc[m][n] = (f32x4){0.f, 0.f, 0.f, 0.f};
  for (int s = 0; s < 4; s++) {
    s16x8 af[2], bf[4];
    #pragma unroll
    for (int m = 0; m < 2; m++)
      af[m] = *(const s16x8*)(w1 + (size_t)(wv * 32 + m * 16 + lo) * 128 + s * 32 + hi * 8);
    #pragma unroll
    for (int n = 0; n < 4; n++) {
      int t = n * 16 + lo;
      bf[n] = *(const s16x8*)((const char*)sT + t * 256 + ((s * 64 + hi * 16) ^ ((t & 7) << 4)));
    }
    #pragma unroll
    for (int m = 0; m < 2; m++)
      #pragma unroll
      for (int n = 0; n < 4; n++)
        acc[m][n] = __builtin_amdgcn_mfma_f32_16x16x32_bf16(af[m], bf[n], acc[m][n], 0, 0, 0);
  }
  #pragma unroll
  for (int m = 0; m < 2; m++) {
    int c0 = wv * 32 + m * 16 + hi * 4;
    f32x4 bv = *(const f32x4*)(b1 + c0);
    #pragma unroll
    for (int n = 0; n < 4; n++) {
      int t = n * 16 + lo;
      s16x4 pk;
      #pragma unroll
      for (int j = 0; j < 4; j++) pk[j] = (short)f2bf(fmaxf(acc[m][n][j] + bv[j], 0.f));
      *(s16x4*)((char*)s1 + ((size_t)b * T + t0 + t) * 256 + ((c0 * 2) ^ ((t & 7) << 4))) = pk;
    }
  }
}

// ---------------- head2: out = last2 @ s1 + b2, out layout [B][256][T] ----------------
__global__ __launch_bounds__(256, 2)
void head2_kernel(const u16* __restrict__ s1, const u16* __restrict__ w2,
                  const float* __restrict__ b2, float* __restrict__ out) {
  __shared__ u16 s1T[64 * 128];
  const int tid = threadIdx.x, wv = tid >> 6, lane = tid & 63, lo = lane & 15, hi = lane >> 4;
  const int t0 = blockIdx.x * 64, b = blockIdx.y;

  const char* src = (const char*)(s1 + ((size_t)b * T + t0) * 128);
  for (int ch = wv; ch < 16; ch += 4)
    gload_lds16(src + ch * 1024 + lane * 16, (char*)s1T + ch * 1024);
  __syncthreads();

  f32x4 acc[4][4];
  #pragma unroll
  for (int m = 0; m < 4; m++)
    #pragma unroll
    for (int n = 0; n < 4; n++) acc[m][n] = (f32x4){0.f, 0.f, 0.f, 0.f};
  for (int s = 0; s < 4; s++) {
    s16x8 af[4], bf[4];
    #pragma unroll
    for (int m = 0; m < 4; m++)
      af[m] = *(const s16x8*)(w2 + (size_t)(wv * 64 + m * 16 + lo) * 128 + s * 32 + hi * 8);
    #pragma unroll
    for (int n = 0; n < 4; n++) {
      int t = n * 16 + lo;
      bf[n] = *(const s16x8*)((const char*)s1T + t * 256 + ((s * 64 + hi * 16) ^ ((t & 7) << 4)));
    }
    #pragma unroll
    for (int m = 0; m < 4; m++)
      #pragma unroll
      for (int n = 0; n < 4; n++)
        acc[m][n] = __builtin_amdgcn_mfma_f32_16x16x32_bf16(af[m], bf[n], acc[m][n], 0, 0, 0);
  }
  #pragma unroll
  for (int m = 0; m < 4; m++) {
    int c0 = wv * 64 + m * 16 + hi * 4;
    f32x4 bv = *(const f32x4*)(b2 + c0);
    #pragma unroll
    for (int n = 0; n < 4; n++) {
      int t = t0 + n * 16 + lo;
      f32x4 r = acc[m][n] + bv;
      #pragma unroll
      for (int j = 0; j < 4; j++) out[((size_t)b * CIN + c0 + j) * T + t] = r[j];
    }
  }
}

// ---------------------------------------------------------------------------
extern "C" void kernel_launch(void* const* d_in, const int* in_sizes, int n_in,
                              void* d_out, int out_size, void* d_ws, size_t ws_size,
                              hipStream_t stream) {
  const float* x       = (const float*)d_in[0];
  const float* first_w = (const float*)d_in[1];
  const float* first_b = (const float*)d_in[2];
  const float* conv_w  = (const float*)d_in[3];
  const float* conv_b  = (const float*)d_in[4];
  const float* out_w   = (const float*)d_in[5];
  const float* out_b   = (const float*)d_in[6];
  const float* skip_w  = (const float*)d_in[7];
  const float* skip_b  = (const float*)d_in[8];
  const float* last1_w = (const float*)d_in[9];
  const float* last1_b = (const float*)d_in[10];
  const float* last2_w = (const float*)d_in[11];
  const float* last2_b = (const float*)d_in[12];
  float* out = (float*)d_out;

  u16* wsp  = (u16*)d_ws;
  u16* wcv  = wsp;                                  // 24*3*256*128
  u16* wsoB = wcv + (size_t)NL * 3 * 256 * 128;
  u16* wfB  = wsoB + (size_t)NL * 256 * 128;
  u16* w1B  = wfB + 128 * 256;
  u16* w2B  = w1B + 128 * 128;
  u16* hb0  = w2B + 256 * 128;
  u16* hb1  = hb0 + (size_t)B * TP * 128;
  u16* s1   = hb0;                                  // alias: hb0 dead before head1

  float* hf   = (float*)d_out;                      // residual master (in-place)
  float* skip = hf + (size_t)B * T * 128;           // skip accumulator

  cvt_convw<<<NL * 3 * 256 * 128 / 256, 256, 0, stream>>>(conv_w, wcv);
  cvt_sow<<<NL * 256 * 128 / 256, 256, 0, stream>>>(skip_w, out_w, wsoB);
  cvt_plain<<<128, 256, 0, stream>>>(first_w, wfB, 128 * 256);
  cvt_plain<<<64, 256, 0, stream>>>(last1_w, w1B, 128 * 128);
  cvt_plain<<<128, 256, 0, stream>>>(last2_w, w2B, 256 * 128);
  padzero<<<128, 256, 0, stream>>>(hb0);
  padzero<<<128, 256, 0, stream>>>(hb1);

  dim3 g64(T / 64, B), g128(T / TT, B);
  first_kernel<<<g64, 256, 0, stream>>>(x, wfB, first_b, hf, hb0);
  for (int i = 0; i < NL; i++) {
    int d = 1 << (i % 6);
    layer_kernel<<<g128, 512, 0, stream>>>(
        (i & 1) ? hb1 : hb0, (i & 1) ? hb0 : hb1, hf, skip,
        wcv + (size_t)i * 3 * 256 * 128, conv_b + (size_t)i * 256,
        wsoB + (size_t)i * 256 * 128, skip_b + (size_t)i * 128,
        out_b + (size_t)i * 128, d, i == 0 ? 1 : 0);
  }
  head1_kernel<<<g64, 256, 0, stream>>>(skip, w1B, last1_b, s1);
  head2_kernel<<<g64, 256, 0, stream>>>(s1, w2B, last2_b, out);
}

// Round 3
// 759.154 us; speedup vs baseline: 6.6251x; 1.0920x over previous
//
#include <hip/hip_runtime.h>

#define B 4
#define CIN 256
#define T 8192
#define NL 24
#define TP (64 + T + 8)      // padded rows for bf16 h: 64 zero halo + T + 8 overshoot
#define TT 64                // layer kernel time tile
#define SQRT_HALF 0.70710678118654752f
#define SKIP_SCALE 0.20412414523193150f  // (1/24)^0.5

typedef unsigned short u16;
typedef __attribute__((ext_vector_type(4))) float f32x4;
typedef __attribute__((ext_vector_type(8))) short s16x8;
typedef __attribute__((ext_vector_type(4))) short s16x4;

__device__ inline u16 f2bf(float f) {            // RNE float->bf16
  unsigned u = __float_as_uint(f);
  return (u16)((u + 0x7fffu + ((u >> 16) & 1u)) >> 16);
}

__device__ inline void gload_lds16(const void* g, void* l) {
  __builtin_amdgcn_global_load_lds(
      (const __attribute__((address_space(1))) unsigned*)g,
      (__attribute__((address_space(3))) unsigned*)l, 16, 0, 0);
}

__device__ inline float gate_fn(float a, float g) {
  // tanh(a)*sigmoid(g) via v_rcp_f32 (bf16-accuracy). Robust at extremes:
  // exp(-g)->inf => rcp(inf)=0; exp(-2|a|)->0 => tanh->1.
  float e2 = __expf(-2.f * fabsf(a));
  float th = (1.f - e2) * __builtin_amdgcn_rcpf(1.f + e2);
  float sg = __builtin_amdgcn_rcpf(1.f + __expf(-g));
  return copysignf(th, a) * sg;
}

// ---------------- weight prep ----------------
__global__ void cvt_convw(const float* __restrict__ src, u16* __restrict__ dst) {
  int i = blockIdx.x * 256 + threadIdx.x;          // N = 24*3*256*128
  if (i >= NL * 3 * 256 * 128) return;
  int c = i & 127, o = (i >> 7) & 255, kk = (i >> 15) % 3, l = (i >> 15) / 3;
  dst[i] = f2bf(src[(((size_t)l * 256 + o) * 128 + c) * 3 + kk]);
}
__global__ void cvt_sow(const float* __restrict__ skw, const float* __restrict__ otw,
                        u16* __restrict__ dst) {
  int i = blockIdx.x * 256 + threadIdx.x;          // N = 24*256*128
  if (i >= NL * 256 * 128) return;
  int c = i & 127, r = (i >> 7) & 255, l = i >> 15;
  float v = (r < 128) ? skw[((size_t)l * 128 + r) * 128 + c]
                      : otw[((size_t)l * 128 + (r - 128)) * 128 + c];
  dst[i] = f2bf(v);
}
__global__ void cvt_plain(const float* __restrict__ s, u16* __restrict__ d, int n) {
  int i = blockIdx.x * 256 + threadIdx.x;
  if (i < n) d[i] = f2bf(s[i]);
}
__global__ void padzero(u16* __restrict__ hb) {
  int i = blockIdx.x * 256 + threadIdx.x;          // N = 4*64*128
  if (i >= B * 64 * 128) return;
  int c = i & 127, r = (i >> 7) & 63, b = i >> 13;
  hb[((size_t)b * TP + r) * 128 + c] = 0;
}

// ---------------- first 1x1 conv: h = first_w @ x + first_b ----------------
__global__ __launch_bounds__(256, 2)
void first_kernel(const float* __restrict__ x, const u16* __restrict__ wf,
                  const float* __restrict__ fb, float* __restrict__ hf,
                  u16* __restrict__ hb) {
  __shared__ u16 xT[64 * 256];    // 32KB, rows 512B, swizzled
  __shared__ u16 hoT[64 * 128];   // 16KB
  const int tid = threadIdx.x, wv = tid >> 6, lane = tid & 63, lo = lane & 15, hi = lane >> 4;
  const int t0 = blockIdx.x * 64, b = blockIdx.y;

  #pragma unroll
  for (int it = 0; it < 16; it++) {                 // transpose-cvt x tile
    int idx = tid + it * 256;                       // 4096 float4
    int c = idx >> 4, t4 = (idx & 15) << 2;
    f32x4 v = *(const f32x4*)(x + ((size_t)b * CIN + c) * T + t0 + t4);
    #pragma unroll
    for (int i = 0; i < 4; i++) {
      int t = t4 + i;
      *(u16*)((char*)xT + t * 512 + ((c * 2) ^ ((t & 7) << 4))) = f2bf(v[i]);
    }
  }
  __syncthreads();

  f32x4 acc[2][4];
  #pragma unroll
  for (int m = 0; m < 2; m++)
    #pragma unroll
    for (int n = 0; n < 4; n++) acc[m][n] = (f32x4){0.f, 0.f, 0.f, 0.f};

  #pragma unroll
  for (int s = 0; s < 8; s++) {
    s16x8 af[2], bf[4];
    #pragma unroll
    for (int m = 0; m < 2; m++)
      af[m] = *(const s16x8*)(wf + (size_t)(wv * 32 + m * 16 + lo) * CIN + s * 32 + hi * 8);
    #pragma unroll
    for (int n = 0; n < 4; n++) {
      int t = n * 16 + lo;
      bf[n] = *(const s16x8*)((const char*)xT + t * 512 + ((s * 64 + hi * 16) ^ ((t & 7) << 4)));
    }
    #pragma unroll
    for (int m = 0; m < 2; m++)
      #pragma unroll
      for (int n = 0; n < 4; n++)
        acc[m][n] = __builtin_amdgcn_mfma_f32_16x16x32_bf16(af[m], bf[n], acc[m][n], 0, 0, 0);
  }

  #pragma unroll
  for (int m = 0; m < 2; m++) {
    int c0 = wv * 32 + m * 16 + hi * 4;
    f32x4 bv = *(const f32x4*)(fb + c0);
    #pragma unroll
    for (int n = 0; n < 4; n++) {
      int t = n * 16 + lo;
      f32x4 h = acc[m][n] + bv;
      *(f32x4*)(hf + ((size_t)b * T + t0 + t) * 128 + c0) = h;
      s16x4 pk;
      #pragma unroll
      for (int j = 0; j < 4; j++) pk[j] = (short)f2bf(h[j]);
      *(s16x4*)((char*)hoT + t * 256 + ((c0 * 2) ^ ((t & 7) << 4))) = pk;
    }
  }
  __syncthreads();
  u16* gd = hb + ((size_t)b * TP + 64 + t0) * 128;
  #pragma unroll
  for (int i = 0; i < 4; i++)
    *(s16x8*)((char*)gd + (tid + i * 256) * 16) = *(const s16x8*)((const char*)hoT + (tid + i * 256) * 16);
}

// ---------------- fused layer: dilated conv + gate + skip + residual ----------------
// TT=64, 512 threads, LDS 48KB -> 3 blocks/CU capacity, grid 512 -> 2 resident.
__global__ __launch_bounds__(512, 4)
void layer_kernel(const u16* __restrict__ hbin, u16* __restrict__ hbout,
                  float* __restrict__ hf, float* __restrict__ skip,
                  const u16* __restrict__ wcv, const float* __restrict__ cb,
                  const u16* __restrict__ wso, const float* __restrict__ sb,
                  const float* __restrict__ ob, int d, int first) {
  __shared__ u16 h_s[128 * 128];  // 32KB: up to 64+2d(<=64) halo rows
  __shared__ u16 zh[64 * 128];    // 16KB: zT, then reused as hoT
  const int tid = threadIdx.x, wv = tid >> 6, lane = tid & 63, lo = lane & 15, hi = lane >> 4;
  const int t0 = blockIdx.x * TT, b = blockIdx.y;
  const int R = TT + 2 * d;
  const int nch = (R * 256 + 1023) >> 10;  // 1KB chunks

  const char* src = (const char*)(hbin + ((size_t)b * TP + (64 + t0 - 2 * d)) * 128);
  for (int ch = wv; ch < nch; ch += 8)
    gload_lds16(src + ch * 1024 + lane * 16, (char*)h_s + ch * 1024);
  __syncthreads();

  // ---- conv GEMM: wave owns a-rows [wv*16,+16) and g-rows [128+wv*16,+16), all 64 cols
  f32x4 acc[2][4];
  #pragma unroll
  for (int m = 0; m < 2; m++)
    #pragma unroll
    for (int n = 0; n < 4; n++) acc[m][n] = (f32x4){0.f, 0.f, 0.f, 0.f};
  const int oa = wv * 16, og = 128 + wv * 16;

  #pragma unroll
  for (int k = 0; k < 3; k++) {
    const int jb = k * d;
    const int st = ((lo + (k + 6) * d) & 7) << 4;   // (global_t & 7) << 4
    #pragma unroll
    for (int s = 0; s < 4; s++) {
      s16x8 af0 = *(const s16x8*)(wcv + ((size_t)(k * 256 + oa + lo)) * 128 + s * 32 + hi * 8);
      s16x8 af1 = *(const s16x8*)(wcv + ((size_t)(k * 256 + og + lo)) * 128 + s * 32 + hi * 8);
      const int cbyte = s * 64 + hi * 16;
      s16x8 bf[4];
      #pragma unroll
      for (int n = 0; n < 4; n++) {
        int j = n * 16 + lo + jb;
        bf[n] = *(const s16x8*)((const char*)h_s + j * 256 + (cbyte ^ st));
      }
      #pragma unroll
      for (int n = 0; n < 4; n++) {
        acc[0][n] = __builtin_amdgcn_mfma_f32_16x16x32_bf16(af0, bf[n], acc[0][n], 0, 0, 0);
        acc[1][n] = __builtin_amdgcn_mfma_f32_16x16x32_bf16(af1, bf[n], acc[1][n], 0, 0, 0);
      }
    }
  }

  // ---- gate -> zT (bf16, swizzled); acc becomes dead after this
  {
    f32x4 ba = *(const f32x4*)(cb + oa + hi * 4);
    f32x4 bg = *(const f32x4*)(cb + og + hi * 4);
    #pragma unroll
    for (int n = 0; n < 4; n++) {
      int t = n * 16 + lo;
      s16x4 pk;
      #pragma unroll
      for (int j = 0; j < 4; j++)
        pk[j] = (short)f2bf(gate_fn(acc[0][n][j] + ba[j], acc[1][n][j] + bg[j]));
      *(s16x4*)((char*)zh + t * 256 + (((oa + hi * 4) * 2) ^ ((t & 7) << 4))) = pk;
    }
  }
  __syncthreads();

  // ---- skip/out GEMM: combined M=256 rows, wave rows [wv*32,+32) (reuse acc)
  #pragma unroll
  for (int m = 0; m < 2; m++)
    #pragma unroll
    for (int n = 0; n < 4; n++) acc[m][n] = (f32x4){0.f, 0.f, 0.f, 0.f};
  const int ro = wv * 32;
  #pragma unroll
  for (int s = 0; s < 4; s++) {
    s16x8 af0 = *(const s16x8*)(wso + (size_t)(ro + lo) * 128 + s * 32 + hi * 8);
    s16x8 af1 = *(const s16x8*)(wso + (size_t)(ro + 16 + lo) * 128 + s * 32 + hi * 8);
    const int cbyte = s * 64 + hi * 16;
    s16x8 bf[4];
    #pragma unroll
    for (int n = 0; n < 4; n++) {
      int t = n * 16 + lo;
      bf[n] = *(const s16x8*)((const char*)zh + t * 256 + (cbyte ^ ((t & 7) << 4)));
    }
    #pragma unroll
    for (int n = 0; n < 4; n++) {
      acc[0][n] = __builtin_amdgcn_mfma_f32_16x16x32_bf16(af0, bf[n], acc[0][n], 0, 0, 0);
      acc[1][n] = __builtin_amdgcn_mfma_f32_16x16x32_bf16(af1, bf[n], acc[1][n], 0, 0, 0);
    }
  }
  __syncthreads();  // zT dead; zh becomes hoT

  if (wv < 4) {   // skip channels wv*32 + ...
    #pragma unroll
    for (int m = 0; m < 2; m++) {
      int c0 = wv * 32 + m * 16 + hi * 4;
      f32x4 sb4 = *(const f32x4*)(sb + c0);
      #pragma unroll
      for (int n = 0; n < 4; n++) {
        size_t off = ((size_t)b * T + t0 + n * 16 + lo) * 128 + c0;
        f32x4 r = acc[m][n] + sb4;
        if (!first) r += *(const f32x4*)(skip + off);
        *(f32x4*)(skip + off) = r;
      }
    }
  } else {        // residual channels (wv-4)*32 + ...
    #pragma unroll
    for (int m = 0; m < 2; m++) {
      int c0 = (wv - 4) * 32 + m * 16 + hi * 4;
      f32x4 ob4 = *(const f32x4*)(ob + c0);
      #pragma unroll
      for (int n = 0; n < 4; n++) {
        int tl = n * 16 + lo;
        size_t off = ((size_t)b * T + t0 + tl) * 128 + c0;
        f32x4 hn = (acc[m][n] + ob4 + *(const f32x4*)(hf + off)) * SQRT_HALF;
        *(f32x4*)(hf + off) = hn;
        s16x4 pk;
        #pragma unroll
        for (int j = 0; j < 4; j++) pk[j] = (short)f2bf(hn[j]);
        *(s16x4*)((char*)zh + tl * 256 + ((c0 * 2) ^ ((tl & 7) << 4))) = pk;
      }
    }
  }
  __syncthreads();
  u16* gd = hbout + ((size_t)b * TP + 64 + t0) * 128;
  #pragma unroll
  for (int i = 0; i < 2; i++)
    *(s16x8*)((char*)gd + (tid + i * 512) * 16) = *(const s16x8*)((const char*)zh + (tid + i * 512) * 16);
}

// ---------------- head1: s1 = relu(last1 @ relu(skip*scale) + b1) ----------------
__global__ __launch_bounds__(256, 2)
void head1_kernel(const float* __restrict__ skip, const u16* __restrict__ w1,
                  const float* __restrict__ b1, u16* __restrict__ s1) {
  __shared__ u16 sT[64 * 128];
  const int tid = threadIdx.x, wv = tid >> 6, lane = tid & 63, lo = lane & 15, hi = lane >> 4;
  const int t0 = blockIdx.x * 64, b = blockIdx.y;

  #pragma unroll
  for (int it = 0; it < 8; it++) {
    int idx = tid + it * 256;                 // 2048 = 64 rows * 32 f32x4
    int t = idx >> 5, c4 = idx & 31;
    f32x4 v = *(const f32x4*)(skip + ((size_t)b * T + t0 + t) * 128 + c4 * 4);
    s16x4 pk;
    #pragma unroll
    for (int i = 0; i < 4; i++) pk[i] = (short)f2bf(fmaxf(v[i] * SKIP_SCALE, 0.f));
    *(s16x4*)((char*)sT + t * 256 + ((c4 * 8) ^ ((t & 7) << 4))) = pk;
  }
  __syncthreads();

  f32x4 acc[2][4];
  #pragma unroll
  for (int m = 0; m < 2; m++)
    #pragma unroll
    for (int n = 0; n < 4; n++) acc[m][n] = (f32x4){0.f, 0.f, 0.f, 0.f};
  #pragma unroll
  for (int s = 0; s < 4; s++) {
    s16x8 af[2], bf[4];
    #pragma unroll
    for (int m = 0; m < 2; m++)
      af[m] = *(const s16x8*)(w1 + (size_t)(wv * 32 + m * 16 + lo) * 128 + s * 32 + hi * 8);
    #pragma unroll
    for (int n = 0; n < 4; n++) {
      int t = n * 16 + lo;
      bf[n] = *(const s16x8*)((const char*)sT + t * 256 + ((s * 64 + hi * 16) ^ ((t & 7) << 4)));
    }
    #pragma unroll
    for (int m = 0; m < 2; m++)
      #pragma unroll
      for (int n = 0; n < 4; n++)
        acc[m][n] = __builtin_amdgcn_mfma_f32_16x16x32_bf16(af[m], bf[n], acc[m][n], 0, 0, 0);
  }
  #pragma unroll
  for (int m = 0; m < 2; m++) {
    int c0 = wv * 32 + m * 16 + hi * 4;
    f32x4 bv = *(const f32x4*)(b1 + c0);
    #pragma unroll
    for (int n = 0; n < 4; n++) {
      int t = n * 16 + lo;
      s16x4 pk;
      #pragma unroll
      for (int j = 0; j < 4; j++) pk[j] = (short)f2bf(fmaxf(acc[m][n][j] + bv[j], 0.f));
      *(s16x4*)((char*)s1 + ((size_t)b * T + t0 + t) * 256 + ((c0 * 2) ^ ((t & 7) << 4))) = pk;
    }
  }
}

// ---------------- head2: out = last2 @ s1 + b2, out layout [B][256][T] ----------------
__global__ __launch_bounds__(256, 2)
void head2_kernel(const u16* __restrict__ s1, const u16* __restrict__ w2,
                  const float* __restrict__ b2, float* __restrict__ out) {
  __shared__ u16 s1T[64 * 128];
  const int tid = threadIdx.x, wv = tid >> 6, lane = tid & 63, lo = lane & 15, hi = lane >> 4;
  const int t0 = blockIdx.x * 64, b = blockIdx.y;

  const char* src = (const char*)(s1 + ((size_t)b * T + t0) * 128);
  #pragma unroll
  for (int i = 0; i < 4; i++)
    gload_lds16(src + (wv + i * 4) * 1024 + lane * 16, (char*)s1T + (wv + i * 4) * 1024);
  __syncthreads();

  f32x4 acc[4][4];
  #pragma unroll
  for (int m = 0; m < 4; m++)
    #pragma unroll
    for (int n = 0; n < 4; n++) acc[m][n] = (f32x4){0.f, 0.f, 0.f, 0.f};
  #pragma unroll
  for (int s = 0; s < 4; s++) {
    s16x8 af[4], bf[4];
    #pragma unroll
    for (int m = 0; m < 4; m++)
      af[m] = *(const s16x8*)(w2 + (size_t)(wv * 64 + m * 16 + lo) * 128 + s * 32 + hi * 8);
    #pragma unroll
    for (int n = 0; n < 4; n++) {
      int t = n * 16 + lo;
      bf[n] = *(const s16x8*)((const char*)s1T + t * 256 + ((s * 64 + hi * 16) ^ ((t & 7) << 4)));
    }
    #pragma unroll
    for (int m = 0; m < 4; m++)
      #pragma unroll
      for (int n = 0; n < 4; n++)
        acc[m][n] = __builtin_amdgcn_mfma_f32_16x16x32_bf16(af[m], bf[n], acc[m][n], 0, 0, 0);
  }
  #pragma unroll
  for (int m = 0; m < 4; m++) {
    int c0 = wv * 64 + m * 16 + hi * 4;
    f32x4 bv = *(const f32x4*)(b2 + c0);
    #pragma unroll
    for (int n = 0; n < 4; n++) {
      int t = t0 + n * 16 + lo;
      f32x4 r = acc[m][n] + bv;
      #pragma unroll
      for (int j = 0; j < 4; j++) out[((size_t)b * CIN + c0 + j) * T + t] = r[j];
    }
  }
}

// ---------------------------------------------------------------------------
extern "C" void kernel_launch(void* const* d_in, const int* in_sizes, int n_in,
                              void* d_out, int out_size, void* d_ws, size_t ws_size,
                              hipStream_t stream) {
  const float* x       = (const float*)d_in[0];
  const float* first_w = (const float*)d_in[1];
  const float* first_b = (const float*)d_in[2];
  const float* conv_w  = (const float*)d_in[3];
  const float* conv_b  = (const float*)d_in[4];
  const float* out_w   = (const float*)d_in[5];
  const float* out_b   = (const float*)d_in[6];
  const float* skip_w  = (const float*)d_in[7];
  const float* skip_b  = (const float*)d_in[8];
  const float* last1_w = (const float*)d_in[9];
  const float* last1_b = (const float*)d_in[10];
  const float* last2_w = (const float*)d_in[11];
  const float* last2_b = (const float*)d_in[12];
  float* out = (float*)d_out;

  u16* wsp  = (u16*)d_ws;
  u16* wcv  = wsp;                                  // 24*3*256*128
  u16* wsoB = wcv + (size_t)NL * 3 * 256 * 128;
  u16* wfB  = wsoB + (size_t)NL * 256 * 128;
  u16* w1B  = wfB + 128 * 256;
  u16* w2B  = w1B + 128 * 128;
  u16* hb0  = w2B + 256 * 128;
  u16* hb1  = hb0 + (size_t)B * TP * 128;
  u16* s1   = hb0;                                  // alias: hb0 dead before head1

  float* hf   = (float*)d_out;                      // residual master (in-place)
  float* skip = hf + (size_t)B * T * 128;           // skip accumulator

  cvt_convw<<<NL * 3 * 256 * 128 / 256, 256, 0, stream>>>(conv_w, wcv);
  cvt_sow<<<NL * 256 * 128 / 256, 256, 0, stream>>>(skip_w, out_w, wsoB);
  cvt_plain<<<128, 256, 0, stream>>>(first_w, wfB, 128 * 256);
  cvt_plain<<<64, 256, 0, stream>>>(last1_w, w1B, 128 * 128);
  cvt_plain<<<128, 256, 0, stream>>>(last2_w, w2B, 256 * 128);
  padzero<<<128, 256, 0, stream>>>(hb0);
  padzero<<<128, 256, 0, stream>>>(hb1);

  dim3 g64(T / 64, B), gL(T / TT, B);
  first_kernel<<<g64, 256, 0, stream>>>(x, wfB, first_b, hf, hb0);
  for (int i = 0; i < NL; i++) {
    int d = 1 << (i % 6);
    layer_kernel<<<gL, 512, 0, stream>>>(
        (i & 1) ? hb1 : hb0, (i & 1) ? hb0 : hb1, hf, skip,
        wcv + (size_t)i * 3 * 256 * 128, conv_b + (size_t)i * 256,
        wsoB + (size_t)i * 256 * 128, skip_b + (size_t)i * 128,
        out_b + (size_t)i * 128, d, i == 0 ? 1 : 0);
  }
  head1_kernel<<<g64, 256, 0, stream>>>(skip, w1B, last1_b, s1);
  head2_kernel<<<g64, 256, 0, stream>>>(s1, w2B, last2_b, out);
}